// Round 3
// baseline (337.217 us; speedup 1.0000x reference)
//
#include <hip/hip_runtime.h>
#include <stdint.h>

#define BATCH 128
#define LCOUNT 196
#define LP1 197
#define DIM 1024

typedef __bf16 bf16x8 __attribute__((ext_vector_type(8)));
typedef float f32x4 __attribute__((ext_vector_type(4)));

__device__ inline float bf2f(uint16_t h){ union{uint32_t i; float f;} x; x.i = ((uint32_t)h) << 16; return x.f; }
__device__ inline uint16_t f2bf(float f){
  union{float f; uint32_t u;} x; x.f = f;
  uint32_t r = x.u + 0x7fffu + ((x.u >> 16) & 1u);
  return (uint16_t)(r >> 16);
}
__device__ inline float tanh_fast(float x){
  float e = __expf(2.0f * x);
  return 1.0f - 2.0f / (e + 1.0f);
}

// Build a bf16x8 MFMA fragment from 8 consecutive fp32 values (RNE casts).
__device__ inline bf16x8 frag_from_f32(const float* p){
  float4 v0 = *(const float4*)p;
  float4 v1 = *(const float4*)(p + 4);
  bf16x8 r;
  r[0]=(__bf16)v0.x; r[1]=(__bf16)v0.y; r[2]=(__bf16)v0.z; r[3]=(__bf16)v0.w;
  r[4]=(__bf16)v1.x; r[5]=(__bf16)v1.y; r[6]=(__bf16)v1.z; r[7]=(__bf16)v1.w;
  return r;
}

// ---------------- GEMM: C[m,n] = act(sum_k A[m,k]*W[n,k] + bias[n]) ----------
// M=128, N=1024, K=1024. W is raw fp32 [N,K] (row-major == W^T access).
// A is either raw fp32 [128,1024] or bf16 ws buffer. Block 256 = 4 waves,
// 32x32 block tile, one 16x16 MFMA tile per wave over full K.
struct GemmArgs {
  const void*  A;       // [128,1024] fp32 (a_f32=1) or bf16 (a_f32=0)
  const float* W;       // [1024,1024] fp32
  const float* bias;    // [1024] fp32 (raw input)
  uint16_t* out_bf;     // bf16 out or null
  float*    out_f;      // fp32 out or null
  int a_f32;
  int act;              // 0 none, 1 relu, 2 tanh
};

__global__ __launch_bounds__(256) void gemm_k(GemmArgs g0, GemmArgs g1) {
  GemmArgs g = (blockIdx.z == 0) ? g0 : g1;
  const int K = DIM, N = DIM;
  int wave = threadIdx.x >> 6;
  int lane = threadIdx.x & 63;
  int r    = lane & 15;
  int quad = lane >> 4;
  int m0 = blockIdx.x * 32 + (wave >> 1) * 16;
  int n0 = blockIdx.y * 32 + (wave & 1) * 16;
  const float*    Apf = (const float*)g.A    + (size_t)(m0 + r) * K + quad * 8;
  const uint16_t* Aph = (const uint16_t*)g.A + (size_t)(m0 + r) * K + quad * 8;
  const float*    Wp  = g.W + (size_t)(n0 + r) * K + quad * 8;
  f32x4 acc = {0.f, 0.f, 0.f, 0.f};
  if (g.a_f32) {
    #pragma unroll 8
    for (int k = 0; k < K; k += 32) {
      bf16x8 a = frag_from_f32(Apf + k);
      bf16x8 b = frag_from_f32(Wp + k);
      acc = __builtin_amdgcn_mfma_f32_16x16x32_bf16(a, b, acc, 0, 0, 0);
    }
  } else {
    #pragma unroll 8
    for (int k = 0; k < K; k += 32) {
      bf16x8 a = *(const bf16x8*)(Aph + k);
      bf16x8 b = frag_from_f32(Wp + k);
      acc = __builtin_amdgcn_mfma_f32_16x16x32_bf16(a, b, acc, 0, 0, 0);
    }
  }
  // C/D layout: col = lane&15, row = quad*4 + i   [verified m89/m91]
  int col = n0 + r;
  float bv = g.bias[col];
  #pragma unroll
  for (int i = 0; i < 4; ++i) {
    int row = m0 + quad * 4 + i;
    float v = acc[i] + bv;
    if (g.act == 1) v = fmaxf(v, 0.f);
    else if (g.act == 2) v = tanhf(v);
    size_t idx = (size_t)row * N + col;
    if (g.out_bf) g.out_bf[idx] = f2bf(v);
    if (g.out_f)  g.out_f[idx]  = v;
  }
}

// ---------------- scores[b,l] = dot(tanh(embed_row + hoe[b]), Wa) + ba -------
// One wave per (b,l) row; 4 rows per 256-thread block.
__global__ __launch_bounds__(256) void scores_k(
    const float* __restrict__ cfe,   // [B,196,1024] fp32 (raw input)
    const float* __restrict__ fre,   // [B,1024] fp32 (ws)
    const float* __restrict__ hoe,   // [B,1024] fp32 (ws)
    const float* __restrict__ Wa,    // [1024] fp32 (raw input)
    const float* __restrict__ ba,    // [1] fp32 (raw input)
    float* __restrict__ scores)      // [B,197]
{
  int row  = blockIdx.x * 4 + (threadIdx.x >> 6);
  int lane = threadIdx.x & 63;
  if (row >= BATCH * LP1) return;
  int b = row / LP1;
  int l = row - b * LP1;
  int d0 = lane * 16;

  const float4* xp = (l == 0)
      ? (const float4*)(fre + b * DIM + d0)
      : (const float4*)(cfe + ((size_t)b * LCOUNT + (l - 1)) * DIM + d0);
  const float4* wp = (const float4*)(Wa + d0);
  const float4* hp = (const float4*)(hoe + b * DIM + d0);
  float sum = 0.f;
  #pragma unroll
  for (int q = 0; q < 4; ++q) {
    float4 x = xp[q];
    float4 h = hp[q];
    float4 w = wp[q];
    sum += tanh_fast(x.x + h.x) * w.x;
    sum += tanh_fast(x.y + h.y) * w.y;
    sum += tanh_fast(x.z + h.z) * w.z;
    sum += tanh_fast(x.w + h.w) * w.w;
  }
  #pragma unroll
  for (int off = 32; off > 0; off >>= 1) sum += __shfl_down(sum, off);
  if (lane == 0) scores[row] = sum + ba[0];
}

// ---------------- softmax(scores[b]) fused with visAtt + ho -> attout --------
// grid (128, 4): block handles batch b, 256-dim chunk. Each thread one dim.
__global__ __launch_bounds__(256) void visatt_k(
    const float*    __restrict__ cf,      // [B,196,1024] fp32 (raw input)
    const uint16_t* __restrict__ frb,     // [B,1024] bf16 (ws)
    const float*    __restrict__ hof,     // [B,1024] fp32 (ws)
    const float*    __restrict__ scores,  // [B,197] (ws)
    uint16_t* __restrict__ attout)        // [B,1024] bf16
{
  int b = blockIdx.x, t = threadIdx.x;
  int lane = t & 63, wave = t >> 6;
  __shared__ float pis[LP1];
  __shared__ float red[4];

  float v = (t < LP1) ? scores[b * LP1 + t] : -1e30f;
  float m = v;
  #pragma unroll
  for (int off = 32; off > 0; off >>= 1) m = fmaxf(m, __shfl_down(m, off));
  if (lane == 0) red[wave] = m;
  __syncthreads();
  m = fmaxf(fmaxf(red[0], red[1]), fmaxf(red[2], red[3]));
  float e = (t < LP1) ? __expf(v - m) : 0.f;
  float s = e;
  #pragma unroll
  for (int off = 32; off > 0; off >>= 1) s += __shfl_down(s, off);
  __syncthreads();
  if (lane == 0) red[wave] = s;
  __syncthreads();
  s = red[0] + red[1] + red[2] + red[3];
  if (t < LP1) pis[t] = e / s;
  __syncthreads();

  int d = blockIdx.y * 256 + t;
  float acc = pis[0] * bf2f(frb[b * DIM + d]);
  const float* base = cf + (size_t)b * LCOUNT * DIM + d;
  #pragma unroll 4
  for (int l = 0; l < LCOUNT; ++l)
    acc += pis[l + 1] * base[(size_t)l * DIM];
  acc += hof[b * DIM + d];
  attout[b * DIM + d] = f2bf(acc);
}

// ---------------- launch -----------------------------------------------------
extern "C" void kernel_launch(void* const* d_in, const int* in_sizes, int n_in,
                              void* d_out, int out_size, void* d_ws, size_t ws_size,
                              hipStream_t stream) {
  const float* h_out       = (const float*)d_in[0];
  const float* fake_region = (const float*)d_in[1];
  const float* conv_feat   = (const float*)d_in[2];
  const float* conv_feat_e = (const float*)d_in[3];
  const float* W_fr  = (const float*)d_in[4];
  const float* b_fr  = (const float*)d_in[5];
  const float* W_fre = (const float*)d_in[6];
  const float* b_fre = (const float*)d_in[7];
  const float* W_ho  = (const float*)d_in[8];
  const float* b_ho  = (const float*)d_in[9];
  const float* W_hoe = (const float*)d_in[10];
  const float* b_hoe = (const float*)d_in[11];
  const float* W_a   = (const float*)d_in[12];
  const float* b_a   = (const float*)d_in[13];
  const float* W_h   = (const float*)d_in[14];
  const float* b_h   = (const float*)d_in[15];

  char* ws = (char*)d_ws;
  uint16_t* fr_bf  = (uint16_t*)(ws + 0);        // 256 KB bf16 [128,1024]
  uint16_t* ho_bf  = (uint16_t*)(ws + 262144);   // 256 KB
  float*    ho_f   = (float*)   (ws + 524288);   // 512 KB fp32 [128,1024]
  float*    fre_f  = (float*)   (ws + 1048576);  // 512 KB
  float*    hoe_f  = (float*)   (ws + 1572864);  // 512 KB
  float*    scores = (float*)   (ws + 2097152);  // ~100 KB [128,197]
  uint16_t* attout = (uint16_t*)(ws + 2201600);  // 256 KB

  dim3 blk(256);

  // 1: fr = relu(fake_region@W_fr^T+b), ho = tanh(h_out@W_ho^T+b)
  GemmArgs ga{fake_region, W_fr, b_fr, fr_bf, nullptr, 1, 1};
  GemmArgs gb{h_out,       W_ho, b_ho, ho_bf, ho_f,    1, 2};
  gemm_k<<<dim3(4, 32, 2), blk, 0, stream>>>(ga, gb);

  // 2: fr_e = fr@W_fre^T+b, ho_e = ho@W_hoe^T+b  (fp32 outputs)
  GemmArgs gc{fr_bf, W_fre, b_fre, nullptr, fre_f, 0, 0};
  GemmArgs gd{ho_bf, W_hoe, b_hoe, nullptr, hoe_f, 0, 0};
  gemm_k<<<dim3(4, 32, 2), blk, 0, stream>>>(gc, gd);

  // 3: attention scores over L+1 = 197 slots
  int nrows = BATCH * LP1;                      // 25216, divisible by 4
  scores_k<<<dim3(nrows / 4), blk, 0, stream>>>(conv_feat_e, fre_f, hoe_f,
                                                W_a, b_a, scores);

  // 4: softmax + visAtt + ho -> attout (bf16)
  visatt_k<<<dim3(BATCH, 4), blk, 0, stream>>>(conv_feat, fr_bf, ho_f,
                                               scores, attout);

  // 5: h = tanh(attout@W_h^T + b_h) -> d_out (fp32)
  GemmArgs ge{attout, W_h, b_h, nullptr, (float*)d_out, 0, 2};
  gemm_k<<<dim3(4, 32, 1), blk, 0, stream>>>(ge, ge);
}

// Round 4
// 303.237 us; speedup vs baseline: 1.1121x; 1.1121x over previous
//
#include <hip/hip_runtime.h>
#include <stdint.h>

#define BATCH 128
#define LCOUNT 196
#define LP1 197
#define DIM 1024

typedef __bf16 bf16x8 __attribute__((ext_vector_type(8)));
typedef float f32x4 __attribute__((ext_vector_type(4)));

__device__ inline float bf2f(uint16_t h){ union{uint32_t i; float f;} x; x.i = ((uint32_t)h) << 16; return x.f; }
__device__ inline uint32_t f2bf(float f){
  union{float f; uint32_t u;} x; x.f = f;
  uint32_t r = x.u + 0x7fffu + ((x.u >> 16) & 1u);
  return r >> 16;
}
__device__ inline float tanh_fast(float x){
  float e = __expf(2.0f * x);
  return 1.0f - 2.0f / (e + 1.0f);
}

// ---------------- fp32 -> bf16 conversion (weights + activations), once ------
struct CvtSeg { const float* src; uint16_t* dst; int n4; };
struct CvtArgs { CvtSeg d[7]; };

__global__ __launch_bounds__(256) void cvt_k(CvtArgs a) {
  int g = blockIdx.x * 256 + threadIdx.x;
  int base = 0, i = 0;
  #pragma unroll
  for (i = 0; i < 7; ++i) { if (g < base + a.d[i].n4) break; base += a.d[i].n4; }
  if (i >= 7) return;
  int e = (g - base) * 4;
  float4 v = *((const float4*)a.d[i].src + (e >> 2));
  uint2 o;
  o.x = f2bf(v.x) | (f2bf(v.y) << 16);
  o.y = f2bf(v.z) | (f2bf(v.w) << 16);
  *(uint2*)(a.d[i].dst + e) = o;
}

// ---------------- GEMM: C[m,n] = act(sum_k A[m,k]*W[n,k] + bias[n]) ----------
// M=128, N=1024, K=1024, A and W bf16 (pre-converted), direct frag loads.
// Block 256 = 4 waves; 32x32 block tile; one 16x16 MFMA tile per wave over K.
struct GemmArgs {
  const uint16_t* A;     // [128,1024] bf16 (ws)
  const uint16_t* W;     // [1024,1024] bf16 (ws, row-major [N,K])
  const float*    bias;  // [1024] fp32 (raw input)
  uint16_t* out_bf;      // bf16 out or null
  float*    out_f;       // fp32 out or null
  int act;               // 0 none, 1 relu, 2 tanh
};

__global__ __launch_bounds__(256) void gemm_k(GemmArgs g0, GemmArgs g1) {
  GemmArgs g = (blockIdx.z == 0) ? g0 : g1;
  const int K = DIM, N = DIM;
  int wave = threadIdx.x >> 6;
  int lane = threadIdx.x & 63;
  int r    = lane & 15;
  int quad = lane >> 4;
  int m0 = blockIdx.x * 32 + (wave >> 1) * 16;
  int n0 = blockIdx.y * 32 + (wave & 1) * 16;
  const uint16_t* Ap = g.A + (size_t)(m0 + r) * K + quad * 8;
  const uint16_t* Wp = g.W + (size_t)(n0 + r) * K + quad * 8;
  f32x4 acc = {0.f, 0.f, 0.f, 0.f};
  #pragma unroll 8
  for (int k = 0; k < K; k += 32) {
    bf16x8 a = *(const bf16x8*)(Ap + k);
    bf16x8 b = *(const bf16x8*)(Wp + k);
    acc = __builtin_amdgcn_mfma_f32_16x16x32_bf16(a, b, acc, 0, 0, 0);
  }
  // C/D layout: col = lane&15, row = quad*4 + i   [verified m89/m91]
  int col = n0 + r;
  float bv = g.bias[col];
  #pragma unroll
  for (int i = 0; i < 4; ++i) {
    int row = m0 + quad * 4 + i;
    float v = acc[i] + bv;
    if (g.act == 1) v = fmaxf(v, 0.f);
    else if (g.act == 2) v = tanhf(v);
    size_t idx = (size_t)row * N + col;
    if (g.out_bf) g.out_bf[idx] = (uint16_t)f2bf(v);
    if (g.out_f)  g.out_f[idx]  = v;
  }
}

// ---------------- scores[b,l] = dot(tanh(embed_row + hoe[b]), Wa) + ba -------
// One wave per (b,l) row; 4 rows per 256-thread block.
__global__ __launch_bounds__(256) void scores_k(
    const float* __restrict__ cfe,   // [B,196,1024] fp32 (raw input)
    const float* __restrict__ fre,   // [B,1024] fp32 (ws)
    const float* __restrict__ hoe,   // [B,1024] fp32 (ws)
    const float* __restrict__ Wa,    // [1024] fp32 (raw input)
    const float* __restrict__ ba,    // [1] fp32 (raw input)
    float* __restrict__ scores)      // [B,197]
{
  int row  = blockIdx.x * 4 + (threadIdx.x >> 6);
  int lane = threadIdx.x & 63;
  if (row >= BATCH * LP1) return;
  int b = row / LP1;
  int l = row - b * LP1;
  int d0 = lane * 16;

  const float4* xp = (l == 0)
      ? (const float4*)(fre + b * DIM + d0)
      : (const float4*)(cfe + ((size_t)b * LCOUNT + (l - 1)) * DIM + d0);
  const float4* wp = (const float4*)(Wa + d0);
  const float4* hp = (const float4*)(hoe + b * DIM + d0);
  float sum = 0.f;
  #pragma unroll
  for (int q = 0; q < 4; ++q) {
    float4 x = xp[q];
    float4 h = hp[q];
    float4 w = wp[q];
    sum += tanh_fast(x.x + h.x) * w.x;
    sum += tanh_fast(x.y + h.y) * w.y;
    sum += tanh_fast(x.z + h.z) * w.z;
    sum += tanh_fast(x.w + h.w) * w.w;
  }
  #pragma unroll
  for (int off = 32; off > 0; off >>= 1) sum += __shfl_down(sum, off);
  if (lane == 0) scores[row] = sum + ba[0];
}

// ---------------- softmax(scores[b]) fused with visAtt + ho -> attout --------
// grid (128, 4): block handles batch b, 256-dim chunk. Each thread one dim.
__global__ __launch_bounds__(256) void visatt_k(
    const float*    __restrict__ cf,      // [B,196,1024] fp32 (raw input)
    const uint16_t* __restrict__ frb,     // [B,1024] bf16 (ws)
    const float*    __restrict__ hof,     // [B,1024] fp32 (ws)
    const float*    __restrict__ scores,  // [B,197] (ws)
    uint16_t* __restrict__ attout)        // [B,1024] bf16
{
  int b = blockIdx.x, t = threadIdx.x;
  int lane = t & 63, wave = t >> 6;
  __shared__ float pis[LP1];
  __shared__ float red[4];

  float v = (t < LP1) ? scores[b * LP1 + t] : -1e30f;
  float m = v;
  #pragma unroll
  for (int off = 32; off > 0; off >>= 1) m = fmaxf(m, __shfl_down(m, off));
  if (lane == 0) red[wave] = m;
  __syncthreads();
  m = fmaxf(fmaxf(red[0], red[1]), fmaxf(red[2], red[3]));
  float e = (t < LP1) ? __expf(v - m) : 0.f;
  float s = e;
  #pragma unroll
  for (int off = 32; off > 0; off >>= 1) s += __shfl_down(s, off);
  __syncthreads();
  if (lane == 0) red[wave] = s;
  __syncthreads();
  s = red[0] + red[1] + red[2] + red[3];
  if (t < LP1) pis[t] = e / s;
  __syncthreads();

  int d = blockIdx.y * 256 + t;
  float acc = pis[0] * bf2f(frb[b * DIM + d]);
  const float* base = cf + (size_t)b * LCOUNT * DIM + d;
  #pragma unroll 4
  for (int l = 0; l < LCOUNT; ++l)
    acc += pis[l + 1] * base[(size_t)l * DIM];
  acc += hof[b * DIM + d];
  attout[b * DIM + d] = (uint16_t)f2bf(acc);
}

// ---------------- launch -----------------------------------------------------
extern "C" void kernel_launch(void* const* d_in, const int* in_sizes, int n_in,
                              void* d_out, int out_size, void* d_ws, size_t ws_size,
                              hipStream_t stream) {
  const float* h_out       = (const float*)d_in[0];
  const float* fake_region = (const float*)d_in[1];
  const float* conv_feat   = (const float*)d_in[2];
  const float* conv_feat_e = (const float*)d_in[3];
  const float* W_fr  = (const float*)d_in[4];
  const float* b_fr  = (const float*)d_in[5];
  const float* W_fre = (const float*)d_in[6];
  const float* b_fre = (const float*)d_in[7];
  const float* W_ho  = (const float*)d_in[8];
  const float* b_ho  = (const float*)d_in[9];
  const float* W_hoe = (const float*)d_in[10];
  const float* b_hoe = (const float*)d_in[11];
  const float* W_a   = (const float*)d_in[12];
  const float* b_a   = (const float*)d_in[13];
  const float* W_h   = (const float*)d_in[14];
  const float* b_h   = (const float*)d_in[15];

  char* ws = (char*)d_ws;
  uint16_t* Wfr_bf  = (uint16_t*)(ws + 0);
  uint16_t* Wfre_bf = (uint16_t*)(ws + 2097152);
  uint16_t* Who_bf  = (uint16_t*)(ws + 4194304);
  uint16_t* Whoe_bf = (uint16_t*)(ws + 6291456);
  uint16_t* Wh_bf   = (uint16_t*)(ws + 8388608);
  uint16_t* hout_bf = (uint16_t*)(ws + 10485760);
  uint16_t* freg_bf = (uint16_t*)(ws + 10747904);
  uint16_t* fr_bf   = (uint16_t*)(ws + 11010048);
  uint16_t* ho_bf   = (uint16_t*)(ws + 11272192);
  float*    ho_f    = (float*)   (ws + 11534336);
  float*    fre_f   = (float*)   (ws + 12058624);
  float*    hoe_f   = (float*)   (ws + 12582912);
  float*    scores  = (float*)   (ws + 13107200);
  uint16_t* attout  = (uint16_t*)(ws + 13209600);

  dim3 blk(256);

  // 0: convert weights + activations to bf16 (once, ~30 MB traffic)
  CvtArgs cv;
  cv.d[0] = { W_fr,  Wfr_bf,  1048576/4 };
  cv.d[1] = { W_fre, Wfre_bf, 1048576/4 };
  cv.d[2] = { W_ho,  Who_bf,  1048576/4 };
  cv.d[3] = { W_hoe, Whoe_bf, 1048576/4 };
  cv.d[4] = { W_h,   Wh_bf,   1048576/4 };
  cv.d[5] = { h_out,       hout_bf, 131072/4 };
  cv.d[6] = { fake_region, freg_bf, 131072/4 };
  cvt_k<<<dim3(5376), blk, 0, stream>>>(cv);   // 1376256 groups of 4

  // 1: fr = relu(fake_region@W_fr^T+b), ho = tanh(h_out@W_ho^T+b)
  GemmArgs ga{freg_bf, Wfr_bf, b_fr, fr_bf, nullptr, 1};
  GemmArgs gb{hout_bf, Who_bf, b_ho, ho_bf, ho_f,    2};
  gemm_k<<<dim3(4, 32, 2), blk, 0, stream>>>(ga, gb);

  // 2: fr_e = fr@W_fre^T+b, ho_e = ho@W_hoe^T+b  (fp32 outputs)
  GemmArgs gc{fr_bf, Wfre_bf, b_fre, nullptr, fre_f, 0};
  GemmArgs gd{ho_bf, Whoe_bf, b_hoe, nullptr, hoe_f, 0};
  gemm_k<<<dim3(4, 32, 2), blk, 0, stream>>>(gc, gd);

  // 3: attention scores over L+1 = 197 slots
  int nrows = BATCH * LP1;                      // 25216, divisible by 4
  scores_k<<<dim3(nrows / 4), blk, 0, stream>>>(conv_feat_e, fre_f, hoe_f,
                                                W_a, b_a, scores);

  // 4: softmax + visAtt + ho -> attout (bf16)
  visatt_k<<<dim3(BATCH, 4), blk, 0, stream>>>(conv_feat, fr_bf, ho_f,
                                               scores, attout);

  // 5: h = tanh(attout@W_h^T + b_h) -> d_out (fp32)
  GemmArgs ge{attout, Wh_bf, b_h, nullptr, (float*)d_out, 2};
  gemm_k<<<dim3(4, 32, 1), blk, 0, stream>>>(ge, ge);
}

// Round 5
// 293.564 us; speedup vs baseline: 1.1487x; 1.0330x over previous
//
#include <hip/hip_runtime.h>
#include <stdint.h>

#define BATCH 128
#define LCOUNT 196
#define LP1 197
#define DIM 1024

typedef __bf16 bf16x8 __attribute__((ext_vector_type(8)));
typedef float f32x4 __attribute__((ext_vector_type(4)));

__device__ inline float bf2f(uint16_t h){ union{uint32_t i; float f;} x; x.i = ((uint32_t)h) << 16; return x.f; }
__device__ inline uint32_t f2bf(float f){
  union{float f; uint32_t u;} x; x.f = f;
  uint32_t r = x.u + 0x7fffu + ((x.u >> 16) & 1u);
  return r >> 16;
}
__device__ inline float tanh_fast(float x){
  float e = __expf(2.0f * x);
  return 1.0f - 2.0f / (e + 1.0f);
}

// ---------------- fp32 -> bf16 conversion (weights + activations), once ------
struct CvtSeg { const float* src; uint16_t* dst; int n4; };
struct CvtArgs { CvtSeg d[7]; };

__global__ __launch_bounds__(256) void cvt_k(CvtArgs a) {
  int g = blockIdx.x * 256 + threadIdx.x;
  int base = 0, i = 0;
  #pragma unroll
  for (i = 0; i < 7; ++i) { if (g < base + a.d[i].n4) break; base += a.d[i].n4; }
  if (i >= 7) return;
  int e = (g - base) * 4;
  float4 v = *((const float4*)a.d[i].src + (e >> 2));
  uint2 o;
  o.x = f2bf(v.x) | (f2bf(v.y) << 16);
  o.y = f2bf(v.z) | (f2bf(v.w) << 16);
  *(uint2*)(a.d[i].dst + e) = o;
}

// ---------------- GEMM: C[m,n] = act(sum_k A[m,k]*W[n,k] + bias[n]) ----------
// M=128, N=1024, K=1024, bf16 pre-converted inputs.
// Split-K: block = one 16x16 output tile; each of 4 waves covers K/4 = 256
// (only 8 chained MFMAs), partials reduced via LDS. Grid (8,64,z) = 512/GEMM.
struct GemmArgs {
  const uint16_t* A;     // [128,1024] bf16 (ws)
  const uint16_t* W;     // [1024,1024] bf16 (ws, row-major [N,K])
  const float*    bias;  // [1024] fp32 (raw input)
  uint16_t* out_bf;      // bf16 out or null
  float*    out_f;       // fp32 out or null
  int act;               // 0 none, 1 relu, 2 tanh
};

__global__ __launch_bounds__(256) void gemm_k(GemmArgs g0, GemmArgs g1) {
  GemmArgs g = (blockIdx.z == 0) ? g0 : g1;
  const int K = DIM, N = DIM;
  int wave = threadIdx.x >> 6;          // K-slice index
  int lane = threadIdx.x & 63;
  int r    = lane & 15;
  int quad = lane >> 4;
  int m0 = blockIdx.x * 16;
  int n0 = blockIdx.y * 16;
  const uint16_t* Ap = g.A + (size_t)(m0 + r) * K + wave * 256 + quad * 8;
  const uint16_t* Wp = g.W + (size_t)(n0 + r) * K + wave * 256 + quad * 8;
  f32x4 acc = {0.f, 0.f, 0.f, 0.f};
  #pragma unroll
  for (int k = 0; k < 256; k += 32) {
    bf16x8 a = *(const bf16x8*)(Ap + k);
    bf16x8 b = *(const bf16x8*)(Wp + k);
    acc = __builtin_amdgcn_mfma_f32_16x16x32_bf16(a, b, acc, 0, 0, 0);
  }
  // C/D layout: col = lane&15, row = quad*4 + i   [verified m89/m91]
  __shared__ float lds[4][256];
  int li = lane * 4;
  lds[wave][li+0] = acc[0]; lds[wave][li+1] = acc[1];
  lds[wave][li+2] = acc[2]; lds[wave][li+3] = acc[3];
  __syncthreads();
  int t = threadIdx.x;
  float v = lds[0][t] + lds[1][t] + lds[2][t] + lds[3][t];
  int col = (t >> 2) & 15;               // lane&15 of producer
  int row = (t >> 6) * 4 + (t & 3);      // quad*4 + i of producer
  v += g.bias[n0 + col];
  if (g.act == 1) v = fmaxf(v, 0.f);
  else if (g.act == 2) v = tanhf(v);
  size_t idx = (size_t)(m0 + row) * N + (n0 + col);
  if (g.out_bf) g.out_bf[idx] = (uint16_t)f2bf(v);
  if (g.out_f)  g.out_f[idx]  = v;
}

// ---------------- scores[b,l] = dot(tanh(embed_row + hoe[b]), Wa) + ba -------
// One wave per (b,l) row; 4 rows per 256-thread block.
__global__ __launch_bounds__(256) void scores_k(
    const float* __restrict__ cfe,   // [B,196,1024] fp32 (raw input)
    const float* __restrict__ fre,   // [B,1024] fp32 (ws)
    const float* __restrict__ hoe,   // [B,1024] fp32 (ws)
    const float* __restrict__ Wa,    // [1024] fp32 (raw input)
    const float* __restrict__ ba,    // [1] fp32 (raw input)
    float* __restrict__ scores)      // [B,197]
{
  int row  = blockIdx.x * 4 + (threadIdx.x >> 6);
  int lane = threadIdx.x & 63;
  if (row >= BATCH * LP1) return;
  int b = row / LP1;
  int l = row - b * LP1;
  int d0 = lane * 16;

  const float4* xp = (l == 0)
      ? (const float4*)(fre + b * DIM + d0)
      : (const float4*)(cfe + ((size_t)b * LCOUNT + (l - 1)) * DIM + d0);
  const float4* wp = (const float4*)(Wa + d0);
  const float4* hp = (const float4*)(hoe + b * DIM + d0);
  float sum = 0.f;
  #pragma unroll
  for (int q = 0; q < 4; ++q) {
    float4 x = xp[q];
    float4 h = hp[q];
    float4 w = wp[q];
    sum += tanh_fast(x.x + h.x) * w.x;
    sum += tanh_fast(x.y + h.y) * w.y;
    sum += tanh_fast(x.z + h.z) * w.z;
    sum += tanh_fast(x.w + h.w) * w.w;
  }
  #pragma unroll
  for (int off = 32; off > 0; off >>= 1) sum += __shfl_down(sum, off);
  if (lane == 0) scores[row] = sum + ba[0];
}

// ---------------- softmax(scores[b]) fused with visAtt + ho -> attout --------
// grid (128, 4): block handles batch b, 256-dim chunk. Each thread one dim.
__global__ __launch_bounds__(256) void visatt_k(
    const float*    __restrict__ cf,      // [B,196,1024] fp32 (raw input)
    const uint16_t* __restrict__ frb,     // [B,1024] bf16 (ws)
    const float*    __restrict__ hof,     // [B,1024] fp32 (ws)
    const float*    __restrict__ scores,  // [B,197] (ws)
    uint16_t* __restrict__ attout)        // [B,1024] bf16
{
  int b = blockIdx.x, t = threadIdx.x;
  int lane = t & 63, wave = t >> 6;
  __shared__ float pis[LP1];
  __shared__ float red[4];

  float v = (t < LP1) ? scores[b * LP1 + t] : -1e30f;
  float m = v;
  #pragma unroll
  for (int off = 32; off > 0; off >>= 1) m = fmaxf(m, __shfl_down(m, off));
  if (lane == 0) red[wave] = m;
  __syncthreads();
  m = fmaxf(fmaxf(red[0], red[1]), fmaxf(red[2], red[3]));
  float e = (t < LP1) ? __expf(v - m) : 0.f;
  float s = e;
  #pragma unroll
  for (int off = 32; off > 0; off >>= 1) s += __shfl_down(s, off);
  __syncthreads();
  if (lane == 0) red[wave] = s;
  __syncthreads();
  s = red[0] + red[1] + red[2] + red[3];
  if (t < LP1) pis[t] = e / s;
  __syncthreads();

  int d = blockIdx.y * 256 + t;
  float acc = pis[0] * bf2f(frb[b * DIM + d]);
  const float* base = cf + (size_t)b * LCOUNT * DIM + d;
  #pragma unroll 8
  for (int l = 0; l < LCOUNT; ++l)
    acc += pis[l + 1] * base[(size_t)l * DIM];
  acc += hof[b * DIM + d];
  attout[b * DIM + d] = (uint16_t)f2bf(acc);
}

// ---------------- launch -----------------------------------------------------
extern "C" void kernel_launch(void* const* d_in, const int* in_sizes, int n_in,
                              void* d_out, int out_size, void* d_ws, size_t ws_size,
                              hipStream_t stream) {
  const float* h_out       = (const float*)d_in[0];
  const float* fake_region = (const float*)d_in[1];
  const float* conv_feat   = (const float*)d_in[2];
  const float* conv_feat_e = (const float*)d_in[3];
  const float* W_fr  = (const float*)d_in[4];
  const float* b_fr  = (const float*)d_in[5];
  const float* W_fre = (const float*)d_in[6];
  const float* b_fre = (const float*)d_in[7];
  const float* W_ho  = (const float*)d_in[8];
  const float* b_ho  = (const float*)d_in[9];
  const float* W_hoe = (const float*)d_in[10];
  const float* b_hoe = (const float*)d_in[11];
  const float* W_a   = (const float*)d_in[12];
  const float* b_a   = (const float*)d_in[13];
  const float* W_h   = (const float*)d_in[14];
  const float* b_h   = (const float*)d_in[15];

  char* ws = (char*)d_ws;
  uint16_t* Wfr_bf  = (uint16_t*)(ws + 0);
  uint16_t* Wfre_bf = (uint16_t*)(ws + 2097152);
  uint16_t* Who_bf  = (uint16_t*)(ws + 4194304);
  uint16_t* Whoe_bf = (uint16_t*)(ws + 6291456);
  uint16_t* Wh_bf   = (uint16_t*)(ws + 8388608);
  uint16_t* hout_bf = (uint16_t*)(ws + 10485760);
  uint16_t* freg_bf = (uint16_t*)(ws + 10747904);
  uint16_t* fr_bf   = (uint16_t*)(ws + 11010048);
  uint16_t* ho_bf   = (uint16_t*)(ws + 11272192);
  float*    ho_f    = (float*)   (ws + 11534336);
  float*    fre_f   = (float*)   (ws + 12058624);
  float*    hoe_f   = (float*)   (ws + 12582912);
  float*    scores  = (float*)   (ws + 13107200);
  uint16_t* attout  = (uint16_t*)(ws + 13209600);

  dim3 blk(256);

  // 0: convert weights + activations to bf16 (once, ~30 MB traffic)
  CvtArgs cv;
  cv.d[0] = { W_fr,  Wfr_bf,  1048576/4 };
  cv.d[1] = { W_fre, Wfre_bf, 1048576/4 };
  cv.d[2] = { W_ho,  Who_bf,  1048576/4 };
  cv.d[3] = { W_hoe, Whoe_bf, 1048576/4 };
  cv.d[4] = { W_h,   Wh_bf,   1048576/4 };
  cv.d[5] = { h_out,       hout_bf, 131072/4 };
  cv.d[6] = { fake_region, freg_bf, 131072/4 };
  cvt_k<<<dim3(5376), blk, 0, stream>>>(cv);   // 1376256 groups of 4

  // 1: fr = relu(fake_region@W_fr^T+b), ho = tanh(h_out@W_ho^T+b)
  GemmArgs ga{freg_bf, Wfr_bf, b_fr, fr_bf, nullptr, 1};
  GemmArgs gb{hout_bf, Who_bf, b_ho, ho_bf, ho_f,    2};
  gemm_k<<<dim3(8, 64, 2), blk, 0, stream>>>(ga, gb);

  // 2: fr_e = fr@W_fre^T+b, ho_e = ho@W_hoe^T+b  (fp32 outputs)
  GemmArgs gc{fr_bf, Wfre_bf, b_fre, nullptr, fre_f, 0};
  GemmArgs gd{ho_bf, Whoe_bf, b_hoe, nullptr, hoe_f, 0};
  gemm_k<<<dim3(8, 64, 2), blk, 0, stream>>>(gc, gd);

  // 3: attention scores over L+1 = 197 slots
  int nrows = BATCH * LP1;                      // 25216, divisible by 4
  scores_k<<<dim3(nrows / 4), blk, 0, stream>>>(conv_feat_e, fre_f, hoe_f,
                                                W_a, b_a, scores);

  // 4: softmax + visAtt + ho -> attout (bf16)
  visatt_k<<<dim3(BATCH, 4), blk, 0, stream>>>(conv_feat, fr_bf, ho_f,
                                               scores, attout);

  // 5: h = tanh(attout@W_h^T + b_h) -> d_out (fp32)
  GemmArgs ge{attout, Wh_bf, b_h, nullptr, (float*)d_out, 2};
  gemm_k<<<dim3(8, 64, 1), blk, 0, stream>>>(ge, ge);
}